// Round 12
// baseline (1883.461 us; speedup 1.0000x reference)
//
#include <hip/hip_runtime.h>
#include <hip/hip_bf16.h>
#include <math.h>

// ---------------------------------------------------------------------------
// GPT-style transformer forward. Round 12: gload_lds B-staging (shuffled
// pool) + fused reduce+LN + conditional bf16 LM head.
// L=4, H=12, HD=64, D=768, V=50257, B=1, T=2048
// Round-11 (MFMA flash) WIN: 2491->1807. Remaining: GEMM core ~355 TF
// (MfmaUtil 15%) across LMH 445us + ~340us/4-layers.
// Changes:
//  (1) k_mm_bf: B staged via 2x1KB contiguous global_load_lds per wave from
//      a SHUFFLED weight pool (round-8 layout, proven correct); A staging
//      unchanged (reg-staged, threads 0-127, VGPR ~76). 512->64 B-side
//      line-requests per K-step, zero B staging VALU. Round-8's regression
//      was the bundled direct-reg A (VGPR 124), not this.
//  (2) k_redln: split-K reduce + bias + residual + LayerNorm fused (block
//      per row, two-pass variance). Saves 2 launches + 2 x-reads/layer.
//  (3) If ws_size fits (runtime check), emb pre-cast to shuffled bf16 in
//      d_ws -> LM head runs the all-bf16 k_mm_bf (half fetch, no conv VALU);
//      else round-10 k_mm_lmh fallback.
// ---------------------------------------------------------------------------

typedef __attribute__((ext_vector_type(8))) short bf16x8;
typedef __attribute__((ext_vector_type(4))) float f32x4;
typedef unsigned short u16;

constexpr int OSZ   = 589824;        // 768*768
constexpr int QKVSZ = 3 * OSZ;
constexpr int W1SZ  = 2359296;       // 3072*768
constexpr int PER_L = QKVSZ + OSZ + W1SZ + W1SZ;  // 7077888

__device__ __forceinline__ u16 f2bf(float f) {
  unsigned u = __float_as_uint(f);
  u += 0x7FFFu + ((u >> 16) & 1u);
  return (u16)(u >> 16);
}

__device__ __forceinline__ float gelu_exact(float v) {
  return 0.5f * v * (1.0f + erff(v * 0.70710678118654752f));
}

__device__ __forceinline__ void gload16(const void* g, void* l) {
  __builtin_amdgcn_global_load_lds(
      (const __attribute__((address_space(1))) unsigned int*)g,
      (__attribute__((address_space(3))) unsigned int*)l, 16, 0, 0);
}

__device__ __forceinline__ int xcd_swizzle(int orig, int nwg) {
  int xcd = orig & 7, lid = orig >> 3;
  int q8 = nwg >> 3, r8 = nwg & 7;
  return (xcd < r8 ? xcd * (q8 + 1) : r8 * (q8 + 1) + (xcd - r8) * q8) + lid;
}

// Shuffled pool offset for element (n,k) of an [N,K] matrix:
// tile (n>>7, k>>5) of 4096 elems; within: plane (k>>3)&3, row n&127, e k&7.
__device__ __forceinline__ unsigned shuf_off(unsigned n, unsigned k, unsigned K) {
  return (((n >> 7) * (K >> 5) + (k >> 5)) << 12) + (((k >> 3) & 3) << 10) +
         ((n & 127) << 3) + (k & 7);
}

__global__ __launch_bounds__(256) void k_embed(const int* __restrict__ ids,
                                               const float* __restrict__ emb,
                                               float* __restrict__ x,
                                               int T, int D) {
  int t = blockIdx.x;
  int id = ids[t];
  float neg_log = -logf(10000.0f) / (float)D;
  for (int d = threadIdx.x; d < D; d += 256) {
    float freq = expf((float)(d & ~1) * neg_log);
    float ang = (float)t * freq;
    float pe = (d & 1) ? cosf(ang) : sinf(ang);
    x[(size_t)t * D + d] = emb[(size_t)id * D + d] + pe;
  }
}

__global__ __launch_bounds__(256) void k_layernorm(const float* __restrict__ x,
                                                   const float* __restrict__ g,
                                                   const float* __restrict__ b,
                                                   u16* __restrict__ y,
                                                   int D) {
  int t = blockIdx.x;
  const float* xr = x + (size_t)t * D;
  __shared__ float red[256];
  float s = 0.f;
  for (int d = threadIdx.x; d < D; d += 256) s += xr[d];
  red[threadIdx.x] = s;
  __syncthreads();
  for (int st = 128; st > 0; st >>= 1) {
    if (threadIdx.x < st) red[threadIdx.x] += red[threadIdx.x + st];
    __syncthreads();
  }
  float mean = red[0] / (float)D;
  __syncthreads();
  float s2 = 0.f;
  for (int d = threadIdx.x; d < D; d += 256) {
    float u = xr[d] - mean;
    s2 += u * u;
  }
  red[threadIdx.x] = s2;
  __syncthreads();
  for (int st = 128; st > 0; st >>= 1) {
    if (threadIdx.x < st) red[threadIdx.x] += red[threadIdx.x + st];
    __syncthreads();
  }
  float rstd = rsqrtf(red[0] / (float)D + 1e-5f);
  u16* yr = y + (size_t)t * D;
  for (int d = threadIdx.x; d < D; d += 256)
    yr[d] = f2bf((xr[d] - mean) * rstd * g[d] + b[d]);
}

// Weight cast: fp32 -> bf16 SHUFFLED pool (round-8 layout, proven).
__global__ __launch_bounds__(256) void k_castw(const float* __restrict__ Wq,
                                               const float* __restrict__ Wk,
                                               const float* __restrict__ Wv,
                                               const float* __restrict__ Wo,
                                               const float* __restrict__ W1,
                                               const float* __restrict__ W2,
                                               u16* __restrict__ pool) {
  unsigned i8 = (blockIdx.x * 256u + threadIdx.x) * 8u;
  unsigned l = i8 / (unsigned)PER_L;
  unsigned off = i8 - l * (unsigned)PER_L;
  const float* src;
  unsigned n, k, K, base;
  if (off < (unsigned)QKVSZ) {
    unsigned w = off / (unsigned)OSZ;
    unsigned o = off - w * (unsigned)OSZ;
    unsigned nl = o / 768u; k = o - nl * 768u;
    src = (w == 0 ? Wq : (w == 1 ? Wk : Wv)) + (size_t)l * OSZ + o;
    n = w * 768u + nl; K = 768u; base = 0u;
  } else if (off < (unsigned)(QKVSZ + OSZ)) {
    unsigned o = off - QKVSZ; n = o / 768u; k = o - n * 768u;
    src = Wo + (size_t)l * OSZ + o; K = 768u; base = QKVSZ;
  } else if (off < (unsigned)(QKVSZ + OSZ + W1SZ)) {
    unsigned o = off - (QKVSZ + OSZ); n = o / 768u; k = o - n * 768u;
    src = W1 + (size_t)l * W1SZ + o; K = 768u; base = QKVSZ + OSZ;
  } else {
    unsigned o = off - (QKVSZ + OSZ + W1SZ); n = o / 3072u; k = o - n * 3072u;
    src = W2 + (size_t)l * W1SZ + o; K = 3072u; base = QKVSZ + OSZ + W1SZ;
  }
  float4 a = *(const float4*)src;
  float4 b = *(const float4*)(src + 4);
  union { bf16x8 v; u16 u[8]; } r;
  r.u[0] = f2bf(a.x); r.u[1] = f2bf(a.y); r.u[2] = f2bf(a.z); r.u[3] = f2bf(a.w);
  r.u[4] = f2bf(b.x); r.u[5] = f2bf(b.y); r.u[6] = f2bf(b.z); r.u[7] = f2bf(b.w);
  *(bf16x8*)(pool + (size_t)l * PER_L + base + shuf_off(n, k, K)) = r.v;
}

__global__ __launch_bounds__(256) void k_castb(const float* __restrict__ bq,
                                               const float* __restrict__ bk,
                                               const float* __restrict__ bv,
                                               float* __restrict__ bqkv) {
  for (int i = threadIdx.x; i < 4 * 2304; i += 256) {
    int l = i / 2304, c = i - l * 2304;
    int w = c / 768, cc = c - w * 768;
    bqkv[i] = (w == 0 ? bq : (w == 1 ? bk : bv))[l * 768 + cc];
  }
}

// emb fp32 [V,768] -> shuffled bf16 pool (393 row-tiles, OOB rows zero).
// One 16B chunk per thread; chunk index = tile*512 + plane*128 + row.
__global__ __launch_bounds__(256) void k_caste(const float* __restrict__ emb,
                                               u16* __restrict__ pool, int V) {
  unsigned gidx = blockIdx.x * 256u + threadIdx.x;  // < 393*24*512
  unsigned tile = gidx >> 9;
  unsigned wi = gidx & 511u;
  unsigned plane = wi >> 7, row = wi & 127u;
  unsigned nb = tile / 24u, ktg = tile - nb * 24u;
  unsigned n = nb * 128u + row;
  unsigned k = ktg * 32u + plane * 8u;
  union { bf16x8 v; u16 u[8]; } r;
  if (n < (unsigned)V) {
    const float* src = emb + (size_t)n * 768 + k;
    float4 a = *(const float4*)src;
    float4 b = *(const float4*)(src + 4);
    r.u[0] = f2bf(a.x); r.u[1] = f2bf(a.y); r.u[2] = f2bf(a.z); r.u[3] = f2bf(a.w);
    r.u[4] = f2bf(b.x); r.u[5] = f2bf(b.y); r.u[6] = f2bf(b.z); r.u[7] = f2bf(b.w);
  } else {
    for (int e = 0; e < 8; ++e) r.u[e] = 0;
  }
  *(bf16x8*)(pool + (size_t)gidx * 8) = r.v;
}

// ---------------------------------------------------------------------------
// k_mm_bf: C[M,N] = A[M,K](bf16 row-major) @ B(SHUFFLED pool)^T + bias.
// mode 0: bias -> fp32 C (col<N guarded); mode 3: fp32 partial (split-K).
// A: reg-staged by threads 0-127 (round-6/10 path, VGPR ~76).
// B: wave w issues 2x contiguous 1KB global_load_lds for plane w of the
//    shuffled tile (64 line-requests/K-step vs 512 row-major).
// One __syncthreads per K-step drains vmcnt (gloads) + lgkm (A stores).
// ---------------------------------------------------------------------------
__global__ __launch_bounds__(256) void k_mm_bf(const u16* __restrict__ A,
                                               const u16* __restrict__ Bp,
                                               const float* __restrict__ bias,
                                               void* __restrict__ Cv,
                                               int M, int N, int K,
                                               int mode, int ks) {
  constexpr int PLANE = 2080;
  constexpr int MATS  = 4 * PLANE;
  constexpr int BUFSZ = 2 * MATS;
  __shared__ alignas(16) unsigned char smem[2 * BUFSZ];

  const int nbx = (N + 127) >> 7;
  const int nby = M >> 7;
  const int swz = xcd_swizzle(blockIdx.x, nbx * nby * ks);
  const int tile = swz / ks;
  const int kb = swz - tile * ks;
  const int nb = tile / nby;
  const int mb = tile - nb * nby;
  const int m0 = mb << 7, n0 = nb << 7;

  const int tid = threadIdx.x;
  const int lane = tid & 63;
  const int w = tid >> 6;
  const int wr = w >> 1, wc = w & 1;

  const int kslot = tid & 3;       // A staging role (tid < 128)
  const int r0 = tid >> 2;         // rows r0 + {0,32,64,96}  (r0 < 32)
  unsigned char* awb0 = smem + kslot * PLANE;

  const int lr = lane & 15, lk = lane >> 4;
  const int ardo = lk * PLANE + (wr * 64 + lr) * 16;
  const int brdo = MATS + lk * PLANE + (wc * 64 + lr) * 16;

  f32x4 acc[4][4] = {};
  bf16x8 rg[4];
  const int Kc = K / ks;
  const int NK = Kc >> 5;
  const int K0 = kb * Kc;
  const int KT = K >> 5;           // tiles along K in shuffled pool

  auto LOADA = [&](int kt) {
    if (tid < 128) {
      const int ko = K0 + (kt << 5) + (kslot << 3);
#pragma unroll
      for (int i = 0; i < 4; ++i)
        rg[i] = *(const bf16x8*)(A + (size_t)(m0 + r0 + (i << 5)) * K + ko);
    }
  };
  auto STOREA = [&](int buf) {
    if (tid < 128) {
      unsigned char* wb = awb0 + buf * BUFSZ;
#pragma unroll
      for (int i = 0; i < 4; ++i)
        *(bf16x8*)(wb + (r0 + (i << 5)) * 16) = rg[i];
    }
  };
  auto GLOADB = [&](int buf, int kt) {
    const int ktg = (K0 >> 5) + kt;
    const u16* src = Bp + (((size_t)nb * KT + ktg) << 12) + (w << 10) + (lane << 3);
    unsigned char* dst = smem + buf * BUFSZ + MATS + w * PLANE;
    gload16(src, dst);
    gload16(src + 512, dst + 1024);
  };
  auto COMPUTE = [&](int buf) {
    const unsigned char* base = smem + buf * BUFSZ;
    bf16x8 af[4], bfr[4];
#pragma unroll
    for (int f = 0; f < 4; ++f) {
      af[f]  = *(const bf16x8*)(base + ardo + f * 256);
      bfr[f] = *(const bf16x8*)(base + brdo + f * 256);
    }
#pragma unroll
    for (int fm = 0; fm < 4; ++fm)
#pragma unroll
      for (int fn = 0; fn < 4; ++fn)
        acc[fm][fn] = __builtin_amdgcn_mfma_f32_16x16x32_bf16(
            af[fm], bfr[fn], acc[fm][fn], 0, 0, 0);
  };

  GLOADB(0, 0);
  LOADA(0);
  STOREA(0);
  __syncthreads();
  int cur = 0;

  for (int kt = 0; kt < NK; ++kt) {
    if (kt + 1 < NK) {
      GLOADB(cur ^ 1, kt + 1);
      LOADA(kt + 1);
    }
    COMPUTE(cur);
    if (kt + 1 < NK) {
      STOREA(cur ^ 1);
      __syncthreads();
      cur ^= 1;
    }
  }

  const int orow0 = m0 + wr * 64 + (lk << 2);
  const int ocol0 = n0 + wc * 64 + lr;
  if (mode == 3) {
    float* P = (float*)Cv + (size_t)kb * M * N;
#pragma unroll
    for (int fn = 0; fn < 4; ++fn) {
      int col = ocol0 + fn * 16;
      if (col >= N) continue;
#pragma unroll
      for (int fm = 0; fm < 4; ++fm)
#pragma unroll
        for (int j = 0; j < 4; ++j) {
          int row = orow0 + fm * 16 + j;
          P[(size_t)row * N + col] = acc[fm][fn][j];
        }
    }
  } else {
    float* C = (float*)Cv;
#pragma unroll
    for (int fn = 0; fn < 4; ++fn) {
      int col = ocol0 + fn * 16;
      if (col >= N) continue;
      float bv = bias[col];
#pragma unroll
      for (int fm = 0; fm < 4; ++fm)
#pragma unroll
        for (int j = 0; j < 4; ++j) {
          int row = orow0 + fm * 16 + j;
          C[(size_t)row * N + col] = acc[fm][fn][j] + bv;
        }
    }
  }
}

// ---------------------------------------------------------------------------
// k_red: out = sum_k P[k] + bias (+res / gelu / ->bf16). Grid-stride, float4.
// mode 1: +res fp32; mode 2: gelu bf16; mode 3: bf16.
// ---------------------------------------------------------------------------
__global__ __launch_bounds__(256) void k_red(const float* __restrict__ P,
                                             int ks,
                                             const float* __restrict__ bias,
                                             const float* __restrict__ res,
                                             void* __restrict__ out,
                                             int M, int N, int mode) {
  const size_t MN = (size_t)M * N;
  const size_t tot4 = MN >> 2;
  for (size_t i4 = (size_t)blockIdx.x * 256 + threadIdx.x; i4 < tot4;
       i4 += (size_t)gridDim.x * 256) {
    size_t i = i4 << 2;
    int col = (int)(i % (size_t)N);
    float4 s = *(const float4*)(P + i);
    for (int k = 1; k < ks; ++k) {
      float4 p = *(const float4*)(P + (size_t)k * MN + i);
      s.x += p.x; s.y += p.y; s.z += p.z; s.w += p.w;
    }
    s.x += bias[col]; s.y += bias[col + 1];
    s.z += bias[col + 2]; s.w += bias[col + 3];
    if (mode == 1) {
      float4 r = *(const float4*)(res + i);
      s.x += r.x; s.y += r.y; s.z += r.z; s.w += r.w;
      *(float4*)((float*)out + i) = s;
    } else if (mode == 2) {
      ushort4 o;
      o.x = f2bf(gelu_exact(s.x)); o.y = f2bf(gelu_exact(s.y));
      o.z = f2bf(gelu_exact(s.z)); o.w = f2bf(gelu_exact(s.w));
      *(ushort4*)((u16*)out + i) = o;
    } else if (mode == 3) {
      ushort4 o;
      o.x = f2bf(s.x); o.y = f2bf(s.y); o.z = f2bf(s.z); o.w = f2bf(s.w);
      *(ushort4*)((u16*)out + i) = o;
    } else {
      *(float4*)((float*)out + i) = s;
    }
  }
}

// ---------------------------------------------------------------------------
// k_redln: fused split-K reduce + bias + residual + LayerNorm (row=block).
// x_new = sum_k P[k] + bias + x_old  (written to x);
// xnb   = LN(x_new; g,b) bf16.  Two-pass variance. 768 cols, 192 active
// float4 lanes; threads 192-255 join reductions with zeros.
// ---------------------------------------------------------------------------
__global__ __launch_bounds__(256) void k_redln(const float* __restrict__ P,
                                               int ks,
                                               const float* __restrict__ bias,
                                               float* __restrict__ x,
                                               const float* __restrict__ g,
                                               const float* __restrict__ b,
                                               u16* __restrict__ xnb) {
  const int t = blockIdx.x;
  const int c = threadIdx.x;
  const bool act = c < 192;
  const size_t MN = (size_t)2048 * 768;
  const size_t base = (size_t)t * 768 + (c << 2);
  __shared__ float red[256];

  float4 s = make_float4(0.f, 0.f, 0.f, 0.f);
  if (act) {
    s = *(const float4*)(P + base);
    for (int k = 1; k < ks; ++k) {
      float4 p = *(const float4*)(P + (size_t)k * MN + base);
      s.x += p.x; s.y += p.y; s.z += p.z; s.w += p.w;
    }
    int col = c << 2;
    s.x += bias[col]; s.y += bias[col + 1];
    s.z += bias[col + 2]; s.w += bias[col + 3];
    float4 r = *(const float4*)(x + base);
    s.x += r.x; s.y += r.y; s.z += r.z; s.w += r.w;
    *(float4*)(x + base) = s;
  }

  red[c] = act ? (s.x + s.y + s.z + s.w) : 0.f;
  __syncthreads();
  for (int st = 128; st > 0; st >>= 1) {
    if (c < st) red[c] += red[c + st];
    __syncthreads();
  }
  float mean = red[0] / 768.f;
  __syncthreads();
  float q = 0.f;
  if (act) {
    float dx = s.x - mean, dy = s.y - mean, dz = s.z - mean, dw = s.w - mean;
    q = dx * dx + dy * dy + dz * dz + dw * dw;
  }
  red[c] = q;
  __syncthreads();
  for (int st = 128; st > 0; st >>= 1) {
    if (c < st) red[c] += red[c + st];
    __syncthreads();
  }
  float rstd = rsqrtf(red[0] / 768.f + 1e-5f);
  if (act) {
    int col = c << 2;
    ushort4 o;
    o.x = f2bf((s.x - mean) * rstd * g[col]     + b[col]);
    o.y = f2bf((s.y - mean) * rstd * g[col + 1] + b[col + 1]);
    o.z = f2bf((s.z - mean) * rstd * g[col + 2] + b[col + 2]);
    o.w = f2bf((s.w - mean) * rstd * g[col + 3] + b[col + 3]);
    *(ushort4*)(xnb + base) = o;
  }
}

// ---------------------------------------------------------------------------
// k_mm_lmh: LM head fallback (round-10 fp32-B path, 435us measured).
// ---------------------------------------------------------------------------
__global__ __launch_bounds__(256) void k_mm_lmh(const u16* __restrict__ A,
                                                const float* __restrict__ B,
                                                const float* __restrict__ bias,
                                                float* __restrict__ C,
                                                int M, int N, int K) {
  constexpr int PLANE = 2080;
  constexpr int MATS  = 4 * PLANE;
  constexpr int BUFSZ = 2 * MATS;
  __shared__ alignas(16) unsigned char smem[2 * BUFSZ];

  const int nbx = (N + 127) >> 7;
  const int nby = M >> 7;
  const int swz = xcd_swizzle(blockIdx.x, nbx * nby);
  const int nb = swz / nby;
  const int mb = swz - nb * nby;
  const int m0 = mb << 7, n0 = nb << 7;

  const int tid = threadIdx.x;
  const int lane = tid & 63;
  const int wid = tid >> 6;
  const int wr = wid >> 1, wc = wid & 1;

  const int mat = tid >> 7;
  const int ts = tid & 127;
  const int kslot = ts & 3;
  const int r0 = ts >> 2;
  const int gr0 = (mat ? n0 : m0) + r0;
  unsigned char* wb0 = smem + mat * MATS + kslot * PLANE;

  const int lr = lane & 15, lk = lane >> 4;
  const int ardo = lk * PLANE + (wr * 64 + lr) * 16;
  const int brdo = MATS + lk * PLANE + (wc * 64 + lr) * 16;

  f32x4 acc[4][4] = {};
  float4 rg[4][2];
  const int NK = K >> 5;

  auto LOAD = [&](int kt) {
    const int ko = (kt << 5) + (kslot << 3);
    if (mat == 0) {
#pragma unroll
      for (int i = 0; i < 4; ++i)
        rg[i][0] = *(const float4*)(A + (size_t)(gr0 + (i << 5)) * K + ko);
    } else {
#pragma unroll
      for (int i = 0; i < 4; ++i) {
        int grow = gr0 + (i << 5);
        if (grow < N) {
          const float* p = B + (size_t)grow * K + ko;
          rg[i][0] = *(const float4*)p;
          rg[i][1] = *(const float4*)(p + 4);
        }
      }
    }
  };
  auto STORE = [&](int buf) {
    unsigned char* wb = wb0 + buf * BUFSZ;
    if (mat == 0) {
#pragma unroll
      for (int i = 0; i < 4; ++i)
        *(float4*)(wb + (r0 + (i << 5)) * 16) = rg[i][0];
    } else {
#pragma unroll
      for (int i = 0; i < 4; ++i) {
        union { bf16x8 v; u16 u[8]; } r;
        r.u[0] = f2bf(rg[i][0].x); r.u[1] = f2bf(rg[i][0].y);
        r.u[2] = f2bf(rg[i][0].z); r.u[3] = f2bf(rg[i][0].w);
        r.u[4] = f2bf(rg[i][1].x); r.u[5] = f2bf(rg[i][1].y);
        r.u[6] = f2bf(rg[i][1].z); r.u[7] = f2bf(rg[i][1].w);
        *(bf16x8*)(wb + (r0 + (i << 5)) * 16) = r.v;
      }
    }
  };
  auto COMPUTE = [&](int buf) {
    const unsigned char* base = smem + buf * BUFSZ;
    bf16x8 af[4], bfr[4];
#pragma unroll
    for (int f = 0; f < 4; ++f) {
      af[f]  = *(const bf16x8*)(base + ardo + f * 256);
      bfr[f] = *(const bf16x8*)(base + brdo + f * 256);
    }
#pragma unroll
    for (int fm = 0; fm < 4; ++fm)
#pragma unroll
      for (int fn = 0; fn < 4; ++fn)
        acc[fm][fn] = __builtin_amdgcn_mfma_f32_16x16x32_bf16(
            af[fm], bfr[fn], acc[fm][fn], 0, 0, 0);
  };

#pragma unroll
  for (int i = 0; i < 4; ++i) {
    rg[i][0] = make_float4(0.f, 0.f, 0.f, 0.f);
    rg[i][1] = make_float4(0.f, 0.f, 0.f, 0.f);
  }
  LOAD(0);
  STORE(0);
  __syncthreads();
  int cur = 0;

  for (int kt = 0; kt < NK; ++kt) {
    if (kt + 1 < NK) LOAD(kt + 1);
    COMPUTE(cur);
    if (kt + 1 < NK) {
      STORE(cur ^ 1);
      __syncthreads();
      cur ^= 1;
    }
  }

  const int orow0 = m0 + wr * 64 + (lk << 2);
  const int ocol0 = n0 + wc * 64 + lr;
#pragma unroll
  for (int fn = 0; fn < 4; ++fn) {
    int col = ocol0 + fn * 16;
    if (col >= N) continue;
    float bv = bias[col];
#pragma unroll
    for (int fm = 0; fm < 4; ++fm)
#pragma unroll
      for (int j = 0; j < 4; ++j) {
        int row = orow0 + fm * 16 + j;
        C[(size_t)row * N + col] = acc[fm][fn][j] + bv;
      }
  }
}

// ---------------------------------------------------------------------------
// k_flashm: MFMA flash attention (round-11, unchanged).
// ---------------------------------------------------------------------------
__global__ __launch_bounds__(256) void k_flashm(const u16* __restrict__ qkv,
                                                u16* __restrict__ ctx,
                                                int T, float scale) {
  constexpr int PITCH = 176;
  __shared__ alignas(16) unsigned char KT[64 * PITCH];
  __shared__ alignas(16) unsigned char VT[64 * PITCH];
  __shared__ alignas(16) unsigned char PS[4][16 * PITCH];

  const int tid = threadIdx.x;
  const int lane = tid & 63;
  const int w = tid >> 6;
  const int lr = lane & 15, lk = lane >> 4;
  const int qt = gridDim.x - 1 - blockIdx.x;
  const int q0 = qt << 6;
  const int hoff = blockIdx.y << 6;

  bf16x8 qf0, qf1;
  {
    const u16* qp = qkv + (size_t)(q0 + w * 16 + lr) * 2304 + hoff + (lk << 3);
    qf0 = *(const bf16x8*)qp;
    qf1 = *(const bf16x8*)(qp + 32);
  }

  float mrow[4] = {-1e30f, -1e30f, -1e30f, -1e30f};
  float lrow[4] = {0.f, 0.f, 0.f, 0.f};
  f32x4 oacc[4] = {};
  unsigned char* pw = PS[w];

  for (int st = 0; st <= qt; ++st) {
    const int s0 = st << 6;
    __syncthreads();
    for (int c = tid; c < 512; c += 256) {
      int row = c >> 3, slot = c & 7;
      const u16* kp = qkv + (size_t)(s0 + row) * 2304 + hoff + 768 + (slot << 3);
      *(bf16x8*)(KT + row * PITCH + (slot << 4)) = *(const bf16x8*)kp;
      union { bf16x8 v; u16 u[8]; } vv;
      vv.v = *(const bf16x8*)(kp + 768);
#pragma unroll
      for (int e = 0; e < 8; ++e)
        *(u16*)(VT + ((slot << 3) + e) * PITCH + (row << 1)) = vv.u[e];
    }
    __syncthreads();

    f32x4 s[4] = {};
#pragma unroll
    for (int fn = 0; fn < 4; ++fn) {
      bf16x8 kf0 = *(const bf16x8*)(KT + (fn * 16 + lr) * PITCH + (lk << 4));
      bf16x8 kf1 = *(const bf16x8*)(KT + (fn * 16 + lr) * PITCH + (lk << 4) + 64);
      s[fn] = __builtin_amdgcn_mfma_f32_16x16x32_bf16(qf0, kf0, s[fn], 0, 0, 0);
      s[fn] = __builtin_amdgcn_mfma_f32_16x16x32_bf16(qf1, kf1, s[fn], 0, 0, 0);
    }
#pragma unroll
    for (int fn = 0; fn < 4; ++fn) {
      s[fn][0] *= scale; s[fn][1] *= scale;
      s[fn][2] *= scale; s[fn][3] *= scale;
    }

    if (st == qt) {
#pragma unroll
      for (int fn = 0; fn < 4; ++fn)
#pragma unroll
        for (int j = 0; j < 4; ++j)
          if (fn * 16 + lr > w * 16 + lk * 4 + j) s[fn][j] = -1e30f;
    }

    float alpha[4];
#pragma unroll
    for (int j = 0; j < 4; ++j) {
      float rmax = fmaxf(fmaxf(s[0][j], s[1][j]), fmaxf(s[2][j], s[3][j]));
      rmax = fmaxf(rmax, __shfl_xor(rmax, 1, 64));
      rmax = fmaxf(rmax, __shfl_xor(rmax, 2, 64));
      rmax = fmaxf(rmax, __shfl_xor(rmax, 4, 64));
      rmax = fmaxf(rmax, __shfl_xor(rmax, 8, 64));
      float mn = fmaxf(mrow[j], rmax);
      alpha[j] = __expf(mrow[j] - mn);
      mrow[j] = mn;
      float rs = 0.f;
#pragma unroll
      for (int fn = 0; fn < 4; ++fn) {
        float p = __expf(s[fn][j] - mn);
        s[fn][j] = p;
        rs += p;
      }
      rs += __shfl_xor(rs, 1, 64);
      rs += __shfl_xor(rs, 2, 64);
      rs += __shfl_xor(rs, 4, 64);
      rs += __shfl_xor(rs, 8, 64);
      lrow[j] = lrow[j] * alpha[j] + rs;
      oacc[0][j] *= alpha[j]; oacc[1][j] *= alpha[j];
      oacc[2][j] *= alpha[j]; oacc[3][j] *= alpha[j];
    }

#pragma unroll
    for (int fn = 0; fn < 4; ++fn)
#pragma unroll
      for (int j = 0; j < 4; ++j)
        *(u16*)(pw + (lk * 4 + j) * PITCH + (fn * 16 + lr) * 2) = f2bf(s[fn][j]);

#pragma unroll
    for (int kt = 0; kt < 2; ++kt) {
      bf16x8 pf = *(const bf16x8*)(pw + lr * PITCH + (lk << 4) + kt * 64);
#pragma unroll
      for (int fn = 0; fn < 4; ++fn) {
        bf16x8 vf = *(const bf16x8*)(VT + (fn * 16 + lr) * PITCH + (lk << 4) + kt * 64);
        oacc[fn] = __builtin_amdgcn_mfma_f32_16x16x32_bf16(pf, vf, oacc[fn], 0, 0, 0);
      }
    }
  }

#pragma unroll
  for (int j = 0; j < 4; ++j) {
    float inv = 1.0f / lrow[j];
    u16* cp = ctx + (size_t)(q0 + w * 16 + lk * 4 + j) * 768 + hoff;
#pragma unroll
    for (int fn = 0; fn < 4; ++fn)
      cp[fn * 16 + lr] = f2bf(oacc[fn][j] * inv);
  }
}

extern "C" void kernel_launch(void* const* d_in, const int* in_sizes, int n_in,
                              void* d_out, int out_size, void* d_ws, size_t ws_size,
                              hipStream_t stream) {
  const int T = 2048, D = 768, H = 12, L = 4, V = 50257, D4 = 3072;
  const size_t td = (size_t)T * D;
  const size_t EMBS_ELEMS = (size_t)393 * 24 * 4096;   // shuffled emb bf16

  const int* ids      = (const int*)d_in[0];
  const float* emb    = (const float*)d_in[1];
  const float* lm_bias= (const float*)d_in[2];
  const float* ln1_g  = (const float*)d_in[3];
  const float* ln1_b  = (const float*)d_in[4];
  const float* ln2_g  = (const float*)d_in[5];
  const float* ln2_b  = (const float*)d_in[6];
  const float* Wq     = (const float*)d_in[7];
  const float* bq     = (const float*)d_in[8];
  const float* Wk     = (const float*)d_in[9];
  const float* bk     = (const float*)d_in[10];
  const float* Wv     = (const float*)d_in[11];
  const float* bv     = (const float*)d_in[12];
  const float* Wo     = (const float*)d_in[13];
  const float* bo     = (const float*)d_in[14];
  const float* W1     = (const float*)d_in[15];
  const float* b1     = (const float*)d_in[16];
  const float* W2     = (const float*)d_in[17];
  const float* b2     = (const float*)d_in[18];
  const float* lnf_g  = (const float*)d_in[19];
  const float* lnf_b  = (const float*)d_in[20];
  float* out = (float*)d_out;

  // Scratch:
  //   d_ws: x fp32 [T,768] + xnb bf16 [T,768] (9.4 MB); if ws_size also
  //         fits 77.3 MB, embS (shuffled bf16 emb) lives after xnb and the
  //         LM head runs all-bf16 (embS persists: d_ws untouched by LMH).
  //   d_out front (~195 MB), all dead before the LM head writes out.
  float* x  = (float*)d_ws;
  u16* xnb  = (u16*)(x + td);
  u16* embS = (u16*)((char*)d_ws + td * 4 + td * 2);
  const bool bigws = ws_size >= td * 4 + td * 2 + EMBS_ELEMS * 2 + 64;

  char* cur = (char*)d_out;
  u16* wpool = (u16*)cur;  cur += (size_t)4 * PER_L * 2;
  float* bqkv = (float*)cur; cur += (size_t)4 * 2304 * 4;
  u16* qkvb = (u16*)cur;     cur += (size_t)T * 2304 * 2;
  u16* cbb = (u16*)cur;      cur += td * 2;
  u16* hbb = (u16*)cur;      cur += (size_t)T * D4 * 2;
  float* pqkv = (float*)cur; cur += (size_t)2 * T * 2304 * 4;
  float* pw1 = (float*)cur;  cur += (size_t)2 * T * D4 * 4;
  float* po4 = (float*)cur;  // 4*T*768*4

  dim3 blk(256);

  k_castw<<<(4 * PER_L) / (256 * 8), blk, 0, stream>>>(Wq, Wk, Wv, Wo, W1, W2, wpool);
  k_castb<<<1, blk, 0, stream>>>(bq, bk, bv, bqkv);
  if (bigws)
    k_caste<<<(int)(EMBS_ELEMS / 8 / 256), blk, 0, stream>>>(emb, embS, V);

  k_embed<<<T, blk, 0, stream>>>(ids, emb, x, T, D);

  for (int l = 0; l < L; ++l) {
    const u16* wl = wpool + (size_t)l * PER_L;

    if (l == 0)
      k_layernorm<<<T, blk, 0, stream>>>(x, ln1_g, ln1_b, xnb, D);

    // QKV: split-K=2 -> fp32 partials -> reduce(+bias) to bf16 qkvb
    k_mm_bf<<<18 * 16 * 2, blk, 0, stream>>>(xnb, wl, nullptr, pqkv,
                                             T, 2304, 768, 3, 2);
    k_red<<<2048, blk, 0, stream>>>(pqkv, 2, bqkv + l * 2304, nullptr,
                                    qkvb, T, 2304, 3);

    dim3 ga(T / 64, H);
    k_flashm<<<ga, blk, 0, stream>>>(qkvb, cbb, T, 0.125f);

    // O-proj: split-K=4 -> fused reduce(+bias+res) + LN2 -> x, xnb
    k_mm_bf<<<6 * 16 * 4, blk, 0, stream>>>(cbb, wl + QKVSZ, nullptr, po4,
                                            T, 768, 768, 3, 4);
    k_redln<<<T, blk, 0, stream>>>(po4, 4, bo + l * D, x,
                                   ln2_g + l * D, ln2_b + l * D, xnb);

    // W1: split-K=2 -> reduce(+bias, gelu) to bf16 hbb
    k_mm_bf<<<24 * 16 * 2, blk, 0, stream>>>(xnb, wl + QKVSZ + OSZ, nullptr, pw1,
                                             T, 3072, 768, 3, 2);
    k_red<<<2048, blk, 0, stream>>>(pw1, 2, b1 + l * D4, nullptr,
                                    hbb, T, 3072, 2);

    // W2: split-K=4 -> fused reduce(+bias+res) + LN1(next)/LNf -> x, xnb
    k_mm_bf<<<6 * 16 * 4, blk, 0, stream>>>(hbb, wl + QKVSZ + OSZ + W1SZ, nullptr,
                                            po4, T, 768, 3072, 3, 4);
    const float* ng = (l < L - 1) ? ln1_g + (l + 1) * D : lnf_g;
    const float* nb_ = (l < L - 1) ? ln1_b + (l + 1) * D : lnf_b;
    k_redln<<<T, blk, 0, stream>>>(po4, 4, b2 + l * D, x, ng, nb_, xnb);
  }

  // LM head: bf16 path (shuffled emb in ws) if it fits, else fp32-B fallback
  if (bigws)
    k_mm_bf<<<393 * 16, blk, 0, stream>>>(xnb, embS, lm_bias, out,
                                          T, V, 768, 0, 1);
  else
    k_mm_lmh<<<393 * 16, blk, 0, stream>>>(xnb, emb, lm_bias, out, T, V, 768);
}

// Round 13
// 1802.328 us; speedup vs baseline: 1.0450x; 1.0450x over previous
//
#include <hip/hip_runtime.h>
#include <hip/hip_bf16.h>
#include <math.h>

// ---------------------------------------------------------------------------
// GPT-style transformer forward. Round 13: split the GEMM variants where
// each measured faster.
// L=4, H=12, HD=64, D=768, V=50257, B=1, T=2048
// Round-12 decomposition: bf16-shuffled-gload LM head WIN (443->354us,
// MfmaUtil 18.8); gload B-staging on small layer GEMMs REGRESS (+160us,
// same mechanism as rounds 7/8: B is L2-resident, DMA just serializes the
// barrier). This round: layer GEMMs revert to round-11 reg-staged k_mm_bf
// (linear wpool); LM head keeps round-12 k_mm_gl (shuffled embS + gload);
// k_redln fusion kept (launch/x-read savings, low risk).
// ---------------------------------------------------------------------------

typedef __attribute__((ext_vector_type(8))) short bf16x8;
typedef __attribute__((ext_vector_type(4))) float f32x4;
typedef unsigned short u16;

constexpr int OSZ   = 589824;        // 768*768
constexpr int QKVSZ = 3 * OSZ;
constexpr int W1SZ  = 2359296;       // 3072*768
constexpr int PER_L = QKVSZ + OSZ + W1SZ + W1SZ;  // 7077888

__device__ __forceinline__ u16 f2bf(float f) {
  unsigned u = __float_as_uint(f);
  u += 0x7FFFu + ((u >> 16) & 1u);
  return (u16)(u >> 16);
}

__device__ __forceinline__ float gelu_exact(float v) {
  return 0.5f * v * (1.0f + erff(v * 0.70710678118654752f));
}

__device__ __forceinline__ void gload16(const void* g, void* l) {
  __builtin_amdgcn_global_load_lds(
      (const __attribute__((address_space(1))) unsigned int*)g,
      (__attribute__((address_space(3))) unsigned int*)l, 16, 0, 0);
}

__device__ __forceinline__ int xcd_swizzle(int orig, int nwg) {
  int xcd = orig & 7, lid = orig >> 3;
  int q8 = nwg >> 3, r8 = nwg & 7;
  return (xcd < r8 ? xcd * (q8 + 1) : r8 * (q8 + 1) + (xcd - r8) * q8) + lid;
}

__global__ __launch_bounds__(256) void k_embed(const int* __restrict__ ids,
                                               const float* __restrict__ emb,
                                               float* __restrict__ x,
                                               int T, int D) {
  int t = blockIdx.x;
  int id = ids[t];
  float neg_log = -logf(10000.0f) / (float)D;
  for (int d = threadIdx.x; d < D; d += 256) {
    float freq = expf((float)(d & ~1) * neg_log);
    float ang = (float)t * freq;
    float pe = (d & 1) ? cosf(ang) : sinf(ang);
    x[(size_t)t * D + d] = emb[(size_t)id * D + d] + pe;
  }
}

__global__ __launch_bounds__(256) void k_layernorm(const float* __restrict__ x,
                                                   const float* __restrict__ g,
                                                   const float* __restrict__ b,
                                                   u16* __restrict__ y,
                                                   int D) {
  int t = blockIdx.x;
  const float* xr = x + (size_t)t * D;
  __shared__ float red[256];
  float s = 0.f;
  for (int d = threadIdx.x; d < D; d += 256) s += xr[d];
  red[threadIdx.x] = s;
  __syncthreads();
  for (int st = 128; st > 0; st >>= 1) {
    if (threadIdx.x < st) red[threadIdx.x] += red[threadIdx.x + st];
    __syncthreads();
  }
  float mean = red[0] / (float)D;
  __syncthreads();
  float s2 = 0.f;
  for (int d = threadIdx.x; d < D; d += 256) {
    float u = xr[d] - mean;
    s2 += u * u;
  }
  red[threadIdx.x] = s2;
  __syncthreads();
  for (int st = 128; st > 0; st >>= 1) {
    if (threadIdx.x < st) red[threadIdx.x] += red[threadIdx.x + st];
    __syncthreads();
  }
  float rstd = rsqrtf(red[0] / (float)D + 1e-5f);
  u16* yr = y + (size_t)t * D;
  for (int d = threadIdx.x; d < D; d += 256)
    yr[d] = f2bf((xr[d] - mean) * rstd * g[d] + b[d]);
}

// Weight cast: fp32 -> bf16 LINEAR pool (round-11 layout, layers use this).
__global__ __launch_bounds__(256) void k_castw(const float* __restrict__ Wq,
                                               const float* __restrict__ Wk,
                                               const float* __restrict__ Wv,
                                               const float* __restrict__ Wo,
                                               const float* __restrict__ W1,
                                               const float* __restrict__ W2,
                                               u16* __restrict__ pool) {
  unsigned i8 = (blockIdx.x * 256u + threadIdx.x) * 8u;
  unsigned l = i8 / (unsigned)PER_L;
  unsigned off = i8 - l * (unsigned)PER_L;
  const float* src;
  if (off < (unsigned)QKVSZ) {
    unsigned w = off / (unsigned)OSZ;
    unsigned o = off - w * (unsigned)OSZ;
    src = (w == 0 ? Wq : (w == 1 ? Wk : Wv)) + (size_t)l * OSZ + o;
  } else if (off < (unsigned)(QKVSZ + OSZ)) {
    src = Wo + (size_t)l * OSZ + (off - QKVSZ);
  } else if (off < (unsigned)(QKVSZ + OSZ + W1SZ)) {
    src = W1 + (size_t)l * W1SZ + (off - (QKVSZ + OSZ));
  } else {
    src = W2 + (size_t)l * W1SZ + (off - (QKVSZ + OSZ + W1SZ));
  }
  float4 a = *(const float4*)src;
  float4 b = *(const float4*)(src + 4);
  union { bf16x8 v; u16 u[8]; } r;
  r.u[0] = f2bf(a.x); r.u[1] = f2bf(a.y); r.u[2] = f2bf(a.z); r.u[3] = f2bf(a.w);
  r.u[4] = f2bf(b.x); r.u[5] = f2bf(b.y); r.u[6] = f2bf(b.z); r.u[7] = f2bf(b.w);
  *(bf16x8*)(pool + i8) = r.v;
}

__global__ __launch_bounds__(256) void k_castb(const float* __restrict__ bq,
                                               const float* __restrict__ bk,
                                               const float* __restrict__ bv,
                                               float* __restrict__ bqkv) {
  for (int i = threadIdx.x; i < 4 * 2304; i += 256) {
    int l = i / 2304, c = i - l * 2304;
    int w = c / 768, cc = c - w * 768;
    bqkv[i] = (w == 0 ? bq : (w == 1 ? bk : bv))[l * 768 + cc];
  }
}

// emb fp32 [V,768] -> SHUFFLED bf16 pool for the LM head (round-12, proven).
// tile (n>>7, k>>5); within: plane (k>>3)&3, row n&127. OOB rows zero.
__global__ __launch_bounds__(256) void k_caste(const float* __restrict__ emb,
                                               u16* __restrict__ pool, int V) {
  unsigned gidx = blockIdx.x * 256u + threadIdx.x;  // < 393*24*512
  unsigned tile = gidx >> 9;
  unsigned wi = gidx & 511u;
  unsigned plane = wi >> 7, row = wi & 127u;
  unsigned nb = tile / 24u, ktg = tile - nb * 24u;
  unsigned n = nb * 128u + row;
  unsigned k = ktg * 32u + plane * 8u;
  union { bf16x8 v; u16 u[8]; } r;
  if (n < (unsigned)V) {
    const float* src = emb + (size_t)n * 768 + k;
    float4 a = *(const float4*)src;
    float4 b = *(const float4*)(src + 4);
    r.u[0] = f2bf(a.x); r.u[1] = f2bf(a.y); r.u[2] = f2bf(a.z); r.u[3] = f2bf(a.w);
    r.u[4] = f2bf(b.x); r.u[5] = f2bf(b.y); r.u[6] = f2bf(b.z); r.u[7] = f2bf(b.w);
  } else {
    for (int e = 0; e < 8; ++e) r.u[e] = 0;
  }
  *(bf16x8*)(pool + (size_t)gidx * 8) = r.v;
}

// ---------------------------------------------------------------------------
// k_mm_bf: round-11 layer GEMM (reg-staged A+B, linear pool, split-K).
// mode 3: fp32 partial to P + kb*M*N. M%128==0, N%128==0.
// ---------------------------------------------------------------------------
__global__ __launch_bounds__(256) void k_mm_bf(const u16* __restrict__ A,
                                               const u16* __restrict__ B,
                                               const float* __restrict__ bias,
                                               void* __restrict__ Cv,
                                               int M, int N, int K,
                                               int mode, int ks) {
  constexpr int PLANE = 2080;
  constexpr int MATS  = 4 * PLANE;
  constexpr int BUFSZ = 2 * MATS;
  __shared__ alignas(16) unsigned char smem[2 * BUFSZ];

  const int nbx = (N + 127) >> 7;
  const int nby = M >> 7;
  const int swz = xcd_swizzle(blockIdx.x, nbx * nby * ks);
  const int tile = swz / ks;
  const int kb = swz - tile * ks;
  const int nb = tile / nby;
  const int mb = tile - nb * nby;
  const int m0 = mb << 7, n0 = nb << 7;

  const int tid = threadIdx.x;
  const int lane = tid & 63;
  const int wid = tid >> 6;
  const int wr = wid >> 1, wc = wid & 1;

  const int mat = tid >> 7;
  const int ts = tid & 127;
  const int kslot = ts & 3;
  const int r0 = ts >> 2;
  const u16* gbase = mat ? B : A;
  const int gr0 = (mat ? n0 : m0) + r0;
  unsigned char* wb0 = smem + mat * MATS + kslot * PLANE;

  const int lr = lane & 15, lk = lane >> 4;
  const int ardo = lk * PLANE + (wr * 64 + lr) * 16;
  const int brdo = MATS + lk * PLANE + (wc * 64 + lr) * 16;

  f32x4 acc[4][4] = {};
  bf16x8 rg[4];
  const int Kc = K / ks;
  const int NK = Kc >> 5;
  const int K0 = kb * Kc;

  auto LOAD = [&](int kt) {
    const int ko = K0 + (kt << 5) + (kslot << 3);
#pragma unroll
    for (int i = 0; i < 4; ++i) {
      int grow = gr0 + (i << 5);
      if (mat) grow = min(grow, N - 1);
      rg[i] = *(const bf16x8*)(gbase + (size_t)grow * K + ko);
    }
  };
  auto STORE = [&](int buf) {
    unsigned char* wb = wb0 + buf * BUFSZ;
#pragma unroll
    for (int i = 0; i < 4; ++i)
      *(bf16x8*)(wb + (r0 + (i << 5)) * 16) = rg[i];
  };
  auto COMPUTE = [&](int buf) {
    const unsigned char* base = smem + buf * BUFSZ;
    bf16x8 af[4], bfr[4];
#pragma unroll
    for (int f = 0; f < 4; ++f) {
      af[f]  = *(const bf16x8*)(base + ardo + f * 256);
      bfr[f] = *(const bf16x8*)(base + brdo + f * 256);
    }
#pragma unroll
    for (int fm = 0; fm < 4; ++fm)
#pragma unroll
      for (int fn = 0; fn < 4; ++fn)
        acc[fm][fn] = __builtin_amdgcn_mfma_f32_16x16x32_bf16(
            af[fm], bfr[fn], acc[fm][fn], 0, 0, 0);
  };

  LOAD(0);
  STORE(0);
  __syncthreads();
  int cur = 0;

  for (int kt = 0; kt < NK; ++kt) {
    if (kt + 1 < NK) LOAD(kt + 1);
    COMPUTE(cur);
    if (kt + 1 < NK) {
      STORE(cur ^ 1);
      __syncthreads();
      cur ^= 1;
    }
  }

  const int orow0 = m0 + wr * 64 + (lk << 2);
  const int ocol0 = n0 + wc * 64 + lr;
  if (mode == 3) {
    float* P = (float*)Cv + (size_t)kb * M * N;
#pragma unroll
    for (int fn = 0; fn < 4; ++fn) {
      int col = ocol0 + fn * 16;
      if (col >= N) continue;
#pragma unroll
      for (int fm = 0; fm < 4; ++fm)
#pragma unroll
        for (int j = 0; j < 4; ++j) {
          int row = orow0 + fm * 16 + j;
          P[(size_t)row * N + col] = acc[fm][fn][j];
        }
    }
  } else {
    float* C = (float*)Cv;
#pragma unroll
    for (int fn = 0; fn < 4; ++fn) {
      int col = ocol0 + fn * 16;
      if (col >= N) continue;
      float bv = bias[col];
#pragma unroll
      for (int fm = 0; fm < 4; ++fm)
#pragma unroll
        for (int j = 0; j < 4; ++j) {
          int row = orow0 + fm * 16 + j;
          C[(size_t)row * N + col] = acc[fm][fn][j] + bv;
        }
    }
  }
}

// ---------------------------------------------------------------------------
// k_mm_gl: LM-head GEMM (round-12, measured 354us): A reg-staged (threads
// 0-127), B via 2x contiguous 1KB global_load_lds per wave from the
// SHUFFLED pool. C = A @ B^T + bias, fp32, col<N guarded.
// ---------------------------------------------------------------------------
__global__ __launch_bounds__(256) void k_mm_gl(const u16* __restrict__ A,
                                               const u16* __restrict__ Bp,
                                               const float* __restrict__ bias,
                                               float* __restrict__ C,
                                               int M, int N, int K) {
  constexpr int PLANE = 2080;
  constexpr int MATS  = 4 * PLANE;
  constexpr int BUFSZ = 2 * MATS;
  __shared__ alignas(16) unsigned char smem[2 * BUFSZ];

  const int nbx = (N + 127) >> 7;
  const int nby = M >> 7;
  const int swz = xcd_swizzle(blockIdx.x, nbx * nby);
  const int nb = swz / nby;
  const int mb = swz - nb * nby;
  const int m0 = mb << 7, n0 = nb << 7;

  const int tid = threadIdx.x;
  const int lane = tid & 63;
  const int w = tid >> 6;
  const int wr = w >> 1, wc = w & 1;

  const int kslot = tid & 3;
  const int r0 = tid >> 2;         // < 32 for tid < 128
  unsigned char* awb0 = smem + kslot * PLANE;

  const int lr = lane & 15, lk = lane >> 4;
  const int ardo = lk * PLANE + (wr * 64 + lr) * 16;
  const int brdo = MATS + lk * PLANE + (wc * 64 + lr) * 16;

  f32x4 acc[4][4] = {};
  bf16x8 rg[4];
  const int NK = K >> 5;           // 24

  auto LOADA = [&](int kt) {
    if (tid < 128) {
      const int ko = (kt << 5) + (kslot << 3);
#pragma unroll
      for (int i = 0; i < 4; ++i)
        rg[i] = *(const bf16x8*)(A + (size_t)(m0 + r0 + (i << 5)) * K + ko);
    }
  };
  auto STOREA = [&](int buf) {
    if (tid < 128) {
      unsigned char* wb = awb0 + buf * BUFSZ;
#pragma unroll
      for (int i = 0; i < 4; ++i)
        *(bf16x8*)(wb + (r0 + (i << 5)) * 16) = rg[i];
    }
  };
  auto GLOADB = [&](int buf, int kt) {
    const u16* src = Bp + (((size_t)nb * NK + kt) << 12) + (w << 10) + (lane << 3);
    unsigned char* dst = smem + buf * BUFSZ + MATS + w * PLANE;
    gload16(src, dst);
    gload16(src + 512, dst + 1024);
  };
  auto COMPUTE = [&](int buf) {
    const unsigned char* base = smem + buf * BUFSZ;
    bf16x8 af[4], bfr[4];
#pragma unroll
    for (int f = 0; f < 4; ++f) {
      af[f]  = *(const bf16x8*)(base + ardo + f * 256);
      bfr[f] = *(const bf16x8*)(base + brdo + f * 256);
    }
#pragma unroll
    for (int fm = 0; fm < 4; ++fm)
#pragma unroll
      for (int fn = 0; fn < 4; ++fn)
        acc[fm][fn] = __builtin_amdgcn_mfma_f32_16x16x32_bf16(
            af[fm], bfr[fn], acc[fm][fn], 0, 0, 0);
  };

  GLOADB(0, 0);
  LOADA(0);
  STOREA(0);
  __syncthreads();
  int cur = 0;

  for (int kt = 0; kt < NK; ++kt) {
    if (kt + 1 < NK) {
      GLOADB(cur ^ 1, kt + 1);
      LOADA(kt + 1);
    }
    COMPUTE(cur);
    if (kt + 1 < NK) {
      STOREA(cur ^ 1);
      __syncthreads();
      cur ^= 1;
    }
  }

  const int orow0 = m0 + wr * 64 + (lk << 2);
  const int ocol0 = n0 + wc * 64 + lr;
#pragma unroll
  for (int fn = 0; fn < 4; ++fn) {
    int col = ocol0 + fn * 16;
    if (col >= N) continue;
    float bv = bias[col];
#pragma unroll
    for (int fm = 0; fm < 4; ++fm)
#pragma unroll
      for (int j = 0; j < 4; ++j) {
        int row = orow0 + fm * 16 + j;
        C[(size_t)row * N + col] = acc[fm][fn][j] + bv;
      }
  }
}

// ---------------------------------------------------------------------------
// k_red: out = sum_k P[k] + bias (+gelu / ->bf16). Grid-stride, float4.
// mode 2: gelu bf16; mode 3: bf16.
// ---------------------------------------------------------------------------
__global__ __launch_bounds__(256) void k_red(const float* __restrict__ P,
                                             int ks,
                                             const float* __restrict__ bias,
                                             const float* __restrict__ res,
                                             void* __restrict__ out,
                                             int M, int N, int mode) {
  const size_t MN = (size_t)M * N;
  const size_t tot4 = MN >> 2;
  for (size_t i4 = (size_t)blockIdx.x * 256 + threadIdx.x; i4 < tot4;
       i4 += (size_t)gridDim.x * 256) {
    size_t i = i4 << 2;
    int col = (int)(i % (size_t)N);
    float4 s = *(const float4*)(P + i);
    for (int k = 1; k < ks; ++k) {
      float4 p = *(const float4*)(P + (size_t)k * MN + i);
      s.x += p.x; s.y += p.y; s.z += p.z; s.w += p.w;
    }
    s.x += bias[col]; s.y += bias[col + 1];
    s.z += bias[col + 2]; s.w += bias[col + 3];
    if (mode == 1) {
      float4 r = *(const float4*)(res + i);
      s.x += r.x; s.y += r.y; s.z += r.z; s.w += r.w;
      *(float4*)((float*)out + i) = s;
    } else if (mode == 2) {
      ushort4 o;
      o.x = f2bf(gelu_exact(s.x)); o.y = f2bf(gelu_exact(s.y));
      o.z = f2bf(gelu_exact(s.z)); o.w = f2bf(gelu_exact(s.w));
      *(ushort4*)((u16*)out + i) = o;
    } else if (mode == 3) {
      ushort4 o;
      o.x = f2bf(s.x); o.y = f2bf(s.y); o.z = f2bf(s.z); o.w = f2bf(s.w);
      *(ushort4*)((u16*)out + i) = o;
    } else {
      *(float4*)((float*)out + i) = s;
    }
  }
}

// ---------------------------------------------------------------------------
// k_redln: fused split-K reduce + bias + residual + LayerNorm (row=block).
// ---------------------------------------------------------------------------
__global__ __launch_bounds__(256) void k_redln(const float* __restrict__ P,
                                               int ks,
                                               const float* __restrict__ bias,
                                               float* __restrict__ x,
                                               const float* __restrict__ g,
                                               const float* __restrict__ b,
                                               u16* __restrict__ xnb) {
  const int t = blockIdx.x;
  const int c = threadIdx.x;
  const bool act = c < 192;
  const size_t MN = (size_t)2048 * 768;
  const size_t base = (size_t)t * 768 + (c << 2);
  __shared__ float red[256];

  float4 s = make_float4(0.f, 0.f, 0.f, 0.f);
  if (act) {
    s = *(const float4*)(P + base);
    for (int k = 1; k < ks; ++k) {
      float4 p = *(const float4*)(P + (size_t)k * MN + base);
      s.x += p.x; s.y += p.y; s.z += p.z; s.w += p.w;
    }
    int col = c << 2;
    s.x += bias[col]; s.y += bias[col + 1];
    s.z += bias[col + 2]; s.w += bias[col + 3];
    float4 r = *(const float4*)(x + base);
    s.x += r.x; s.y += r.y; s.z += r.z; s.w += r.w;
    *(float4*)(x + base) = s;
  }

  red[c] = act ? (s.x + s.y + s.z + s.w) : 0.f;
  __syncthreads();
  for (int st = 128; st > 0; st >>= 1) {
    if (c < st) red[c] += red[c + st];
    __syncthreads();
  }
  float mean = red[0] / 768.f;
  __syncthreads();
  float q = 0.f;
  if (act) {
    float dx = s.x - mean, dy = s.y - mean, dz = s.z - mean, dw = s.w - mean;
    q = dx * dx + dy * dy + dz * dz + dw * dw;
  }
  red[c] = q;
  __syncthreads();
  for (int st = 128; st > 0; st >>= 1) {
    if (c < st) red[c] += red[c + st];
    __syncthreads();
  }
  float rstd = rsqrtf(red[0] / 768.f + 1e-5f);
  if (act) {
    int col = c << 2;
    ushort4 o;
    o.x = f2bf((s.x - mean) * rstd * g[col]     + b[col]);
    o.y = f2bf((s.y - mean) * rstd * g[col + 1] + b[col + 1]);
    o.z = f2bf((s.z - mean) * rstd * g[col + 2] + b[col + 2]);
    o.w = f2bf((s.w - mean) * rstd * g[col + 3] + b[col + 3]);
    *(ushort4*)(xnb + base) = o;
  }
}

// ---------------------------------------------------------------------------
// k_mm_lmh: LM head fallback (round-10 fp32-B path) for small ws.
// ---------------------------------------------------------------------------
__global__ __launch_bounds__(256) void k_mm_lmh(const u16* __restrict__ A,
                                                const float* __restrict__ B,
                                                const float* __restrict__ bias,
                                                float* __restrict__ C,
                                                int M, int N, int K) {
  constexpr int PLANE = 2080;
  constexpr int MATS  = 4 * PLANE;
  constexpr int BUFSZ = 2 * MATS;
  __shared__ alignas(16) unsigned char smem[2 * BUFSZ];

  const int nbx = (N + 127) >> 7;
  const int nby = M >> 7;
  const int swz = xcd_swizzle(blockIdx.x, nbx * nby);
  const int nb = swz / nby;
  const int mb = swz - nb * nby;
  const int m0 = mb << 7, n0 = nb << 7;

  const int tid = threadIdx.x;
  const int lane = tid & 63;
  const int wid = tid >> 6;
  const int wr = wid >> 1, wc = wid & 1;

  const int mat = tid >> 7;
  const int ts = tid & 127;
  const int kslot = ts & 3;
  const int r0 = ts >> 2;
  const int gr0 = (mat ? n0 : m0) + r0;
  unsigned char* wb0 = smem + mat * MATS + kslot * PLANE;

  const int lr = lane & 15, lk = lane >> 4;
  const int ardo = lk * PLANE + (wr * 64 + lr) * 16;
  const int brdo = MATS + lk * PLANE + (wc * 64 + lr) * 16;

  f32x4 acc[4][4] = {};
  float4 rg[4][2];
  const int NK = K >> 5;

  auto LOAD = [&](int kt) {
    const int ko = (kt << 5) + (kslot << 3);
    if (mat == 0) {
#pragma unroll
      for (int i = 0; i < 4; ++i)
        rg[i][0] = *(const float4*)(A + (size_t)(gr0 + (i << 5)) * K + ko);
    } else {
#pragma unroll
      for (int i = 0; i < 4; ++i) {
        int grow = gr0 + (i << 5);
        if (grow < N) {
          const float* p = B + (size_t)grow * K + ko;
          rg[i][0] = *(const float4*)p;
          rg[i][1] = *(const float4*)(p + 4);
        }
      }
    }
  };
  auto STORE = [&](int buf) {
    unsigned char* wb = wb0 + buf * BUFSZ;
    if (mat == 0) {
#pragma unroll
      for (int i = 0; i < 4; ++i)
        *(float4*)(wb + (r0 + (i << 5)) * 16) = rg[i][0];
    } else {
#pragma unroll
      for (int i = 0; i < 4; ++i) {
        union { bf16x8 v; u16 u[8]; } r;
        r.u[0] = f2bf(rg[i][0].x); r.u[1] = f2bf(rg[i][0].y);
        r.u[2] = f2bf(rg[i][0].z); r.u[3] = f2bf(rg[i][0].w);
        r.u[4] = f2bf(rg[i][1].x); r.u[5] = f2bf(rg[i][1].y);
        r.u[6] = f2bf(rg[i][1].z); r.u[7] = f2bf(rg[i][1].w);
        *(bf16x8*)(wb + (r0 + (i << 5)) * 16) = r.v;
      }
    }
  };
  auto COMPUTE = [&](int buf) {
    const unsigned char* base = smem + buf * BUFSZ;
    bf16x8 af[4], bfr[4];
#pragma unroll
    for (int f = 0; f < 4; ++f) {
      af[f]  = *(const bf16x8*)(base + ardo + f * 256);
      bfr[f] = *(const bf16x8*)(base + brdo + f * 256);
    }
#pragma unroll
    for (int fm = 0; fm < 4; ++fm)
#pragma unroll
      for (int fn = 0; fn < 4; ++fn)
        acc[fm][fn] = __builtin_amdgcn_mfma_f32_16x16x32_bf16(
            af[fm], bfr[fn], acc[fm][fn], 0, 0, 0);
  };

#pragma unroll
  for (int i = 0; i < 4; ++i) {
    rg[i][0] = make_float4(0.f, 0.f, 0.f, 0.f);
    rg[i][1] = make_float4(0.f, 0.f, 0.f, 0.f);
  }
  LOAD(0);
  STORE(0);
  __syncthreads();
  int cur = 0;

  for (int kt = 0; kt < NK; ++kt) {
    if (kt + 1 < NK) LOAD(kt + 1);
    COMPUTE(cur);
    if (kt + 1 < NK) {
      STORE(cur ^ 1);
      __syncthreads();
      cur ^= 1;
    }
  }

  const int orow0 = m0 + wr * 64 + (lk << 2);
  const int ocol0 = n0 + wc * 64 + lr;
#pragma unroll
  for (int fn = 0; fn < 4; ++fn) {
    int col = ocol0 + fn * 16;
    if (col >= N) continue;
    float bv = bias[col];
#pragma unroll
    for (int fm = 0; fm < 4; ++fm)
#pragma unroll
      for (int j = 0; j < 4; ++j) {
        int row = orow0 + fm * 16 + j;
        C[(size_t)row * N + col] = acc[fm][fn][j] + bv;
      }
  }
}

// ---------------------------------------------------------------------------
// k_flashm: MFMA flash attention (round-11, unchanged).
// ---------------------------------------------------------------------------
__global__ __launch_bounds__(256) void k_flashm(const u16* __restrict__ qkv,
                                                u16* __restrict__ ctx,
                                                int T, float scale) {
  constexpr int PITCH = 176;
  __shared__ alignas(16) unsigned char KT[64 * PITCH];
  __shared__ alignas(16) unsigned char VT[64 * PITCH];
  __shared__ alignas(16) unsigned char PS[4][16 * PITCH];

  const int tid = threadIdx.x;
  const int lane = tid & 63;
  const int w = tid >> 6;
  const int lr = lane & 15, lk = lane >> 4;
  const int qt = gridDim.x - 1 - blockIdx.x;
  const int q0 = qt << 6;
  const int hoff = blockIdx.y << 6;

  bf16x8 qf0, qf1;
  {
    const u16* qp = qkv + (size_t)(q0 + w * 16 + lr) * 2304 + hoff + (lk << 3);
    qf0 = *(const bf16x8*)qp;
    qf1 = *(const bf16x8*)(qp + 32);
  }

  float mrow[4] = {-1e30f, -1e30f, -1e30f, -1e30f};
  float lrow[4] = {0.f, 0.f, 0.f, 0.f};
  f32x4 oacc[4] = {};
  unsigned char* pw = PS[w];

  for (int st = 0; st <= qt; ++st) {
    const int s0 = st << 6;
    __syncthreads();
    for (int c = tid; c < 512; c += 256) {
      int row = c >> 3, slot = c & 7;
      const u16* kp = qkv + (size_t)(s0 + row) * 2304 + hoff + 768 + (slot << 3);
      *(bf16x8*)(KT + row * PITCH + (slot << 4)) = *(const bf16x8*)kp;
      union { bf16x8 v; u16 u[8]; } vv;
      vv.v = *(const bf16x8*)(kp + 768);
#pragma unroll
      for (int e = 0; e < 8; ++e)
        *(u16*)(VT + ((slot << 3) + e) * PITCH + (row << 1)) = vv.u[e];
    }
    __syncthreads();

    f32x4 s[4] = {};
#pragma unroll
    for (int fn = 0; fn < 4; ++fn) {
      bf16x8 kf0 = *(const bf16x8*)(KT + (fn * 16 + lr) * PITCH + (lk << 4));
      bf16x8 kf1 = *(const bf16x8*)(KT + (fn * 16 + lr) * PITCH + (lk << 4) + 64);
      s[fn] = __builtin_amdgcn_mfma_f32_16x16x32_bf16(qf0, kf0, s[fn], 0, 0, 0);
      s[fn] = __builtin_amdgcn_mfma_f32_16x16x32_bf16(qf1, kf1, s[fn], 0, 0, 0);
    }
#pragma unroll
    for (int fn = 0; fn < 4; ++fn) {
      s[fn][0] *= scale; s[fn][1] *= scale;
      s[fn][2] *= scale; s[fn][3] *= scale;
    }

    if (st == qt) {
#pragma unroll
      for (int fn = 0; fn < 4; ++fn)
#pragma unroll
        for (int j = 0; j < 4; ++j)
          if (fn * 16 + lr > w * 16 + lk * 4 + j) s[fn][j] = -1e30f;
    }

    float alpha[4];
#pragma unroll
    for (int j = 0; j < 4; ++j) {
      float rmax = fmaxf(fmaxf(s[0][j], s[1][j]), fmaxf(s[2][j], s[3][j]));
      rmax = fmaxf(rmax, __shfl_xor(rmax, 1, 64));
      rmax = fmaxf(rmax, __shfl_xor(rmax, 2, 64));
      rmax = fmaxf(rmax, __shfl_xor(rmax, 4, 64));
      rmax = fmaxf(rmax, __shfl_xor(rmax, 8, 64));
      float mn = fmaxf(mrow[j], rmax);
      alpha[j] = __expf(mrow[j] - mn);
      mrow[j] = mn;
      float rs = 0.f;
#pragma unroll
      for (int fn = 0; fn < 4; ++fn) {
        float p = __expf(s[fn][j] - mn);
        s[fn][j] = p;
        rs += p;
      }
      rs += __shfl_xor(rs, 1, 64);
      rs += __shfl_xor(rs, 2, 64);
      rs += __shfl_xor(rs, 4, 64);
      rs += __shfl_xor(rs, 8, 64);
      lrow[j] = lrow[j] * alpha[j] + rs;
      oacc[0][j] *= alpha[j]; oacc[1][j] *= alpha[j];
      oacc[2][j] *= alpha[j]; oacc[3][j] *= alpha[j];
    }

#pragma unroll
    for (int fn = 0; fn < 4; ++fn)
#pragma unroll
      for (int j = 0; j < 4; ++j)
        *(u16*)(pw + (lk * 4 + j) * PITCH + (fn * 16 + lr) * 2) = f2bf(s[fn][j]);

#pragma unroll
    for (int kt = 0; kt < 2; ++kt) {
      bf16x8 pf = *(const bf16x8*)(pw + lr * PITCH + (lk << 4) + kt * 64);
#pragma unroll
      for (int fn = 0; fn < 4; ++fn) {
        bf16x8 vf = *(const bf16x8*)(VT + (fn * 16 + lr) * PITCH + (lk << 4) + kt * 64);
        oacc[fn] = __builtin_amdgcn_mfma_f32_16x16x32_bf16(pf, vf, oacc[fn], 0, 0, 0);
      }
    }
  }

#pragma unroll
  for (int j = 0; j < 4; ++j) {
    float inv = 1.0f / lrow[j];
    u16* cp = ctx + (size_t)(q0 + w * 16 + lk * 4 + j) * 768 + hoff;
#pragma unroll
    for (int fn = 0; fn < 4; ++fn)
      cp[fn * 16 + lr] = f2bf(oacc[fn][j] * inv);
  }
}

extern "C" void kernel_launch(void* const* d_in, const int* in_sizes, int n_in,
                              void* d_out, int out_size, void* d_ws, size_t ws_size,
                              hipStream_t stream) {
  const int T = 2048, D = 768, H = 12, L = 4, V = 50257, D4 = 3072;
  const size_t td = (size_t)T * D;
  const size_t EMBS_ELEMS = (size_t)393 * 24 * 4096;   // shuffled emb bf16

  const int* ids      = (const int*)d_in[0];
  const float* emb    = (const float*)d_in[1];
  const float* lm_bias= (const float*)d_in[2];
  const float* ln1_g  = (const float*)d_in[3];
  const float* ln1_b  = (const float*)d_in[4];
  const float* ln2_g  = (const float*)d_in[5];
  const float* ln2_b  = (const float*)d_in[6];
  const float* Wq     = (const float*)d_in[7];
  const float* bq     = (const float*)d_in[8];
  const float* Wk     = (const float*)d_in[9];
  const float* bk     = (const float*)d_in[10];
  const float* Wv     = (const float*)d_in[11];
  const float* bv     = (const float*)d_in[12];
  const float* Wo     = (const float*)d_in[13];
  const float* bo     = (const float*)d_in[14];
  const float* W1     = (const float*)d_in[15];
  const float* b1     = (const float*)d_in[16];
  const float* W2     = (const float*)d_in[17];
  const float* b2     = (const float*)d_in[18];
  const float* lnf_g  = (const float*)d_in[19];
  const float* lnf_b  = (const float*)d_in[20];
  float* out = (float*)d_out;

  // Scratch:
  //   d_ws: x fp32 + xnb bf16 (9.4 MB); if ws fits 77.3 MB, embS (shuffled
  //         bf16 emb) follows and the LM head runs bf16-gload; else fallback.
  //   d_out front (~195 MB), all dead before the LM head writes out.
  float* x  = (float*)d_ws;
  u16* xnb  = (u16*)(x + td);
  u16* embS = (u16*)((char*)d_ws + td * 4 + td * 2);
  const bool bigws = ws_size >= td * 4 + td * 2 + EMBS_ELEMS * 2 + 64;

  char* cur = (char*)d_out;
  u16* wpool = (u16*)cur;  cur += (size_t)4 * PER_L * 2;
  float* bqkv = (float*)cur; cur += (size_t)4 * 2304 * 4;
  u16* qkvb = (u16*)cur;     cur += (size_t)T * 2304 * 2;
  u16* cbb = (u16*)cur;      cur += td * 2;
  u16* hbb = (u16*)cur;      cur += (size_t)T * D4 * 2;
  float* pqkv = (float*)cur; cur += (size_t)2 * T * 2304 * 4;
  float* pw1 = (float*)cur;  cur += (size_t)2 * T * D4 * 4;
  float* po4 = (float*)cur;  // 4*T*768*4

  dim3 blk(256);

  k_castw<<<(4 * PER_L) / (256 * 8), blk, 0, stream>>>(Wq, Wk, Wv, Wo, W1, W2, wpool);
  k_castb<<<1, blk, 0, stream>>>(bq, bk, bv, bqkv);
  if (bigws)
    k_caste<<<(int)(EMBS_ELEMS / 8 / 256), blk, 0, stream>>>(emb, embS, V);

  k_embed<<<T, blk, 0, stream>>>(ids, emb, x, T, D);

  for (int l = 0; l < L; ++l) {
    const u16* wl = wpool + (size_t)l * PER_L;

    if (l == 0)
      k_layernorm<<<T, blk, 0, stream>>>(x, ln1_g, ln1_b, xnb, D);

    // QKV: split-K=2 -> fp32 partials -> reduce(+bias) to bf16 qkvb
    k_mm_bf<<<18 * 16 * 2, blk, 0, stream>>>(xnb, wl, nullptr, pqkv,
                                             T, 2304, 768, 3, 2);
    k_red<<<2048, blk, 0, stream>>>(pqkv, 2, bqkv + l * 2304, nullptr,
                                    qkvb, T, 2304, 3);

    dim3 ga(T / 64, H);
    k_flashm<<<ga, blk, 0, stream>>>(qkvb, cbb, T, 0.125f);

    // O-proj: split-K=4 -> fused reduce(+bias+res) + LN2 -> x, xnb
    k_mm_bf<<<6 * 16 * 4, blk, 0, stream>>>(cbb, wl + QKVSZ, nullptr, po4,
                                            T, 768, 768, 3, 4);
    k_redln<<<T, blk, 0, stream>>>(po4, 4, bo + l * D, x,
                                   ln2_g + l * D, ln2_b + l * D, xnb);

    // W1: split-K=2 -> reduce(+bias, gelu) to bf16 hbb
    k_mm_bf<<<24 * 16 * 2, blk, 0, stream>>>(xnb, wl + QKVSZ + OSZ, nullptr, pw1,
                                             T, 3072, 768, 3, 2);
    k_red<<<2048, blk, 0, stream>>>(pw1, 2, b1 + l * D4, nullptr,
                                    hbb, T, 3072, 2);

    // W2: split-K=4 -> fused reduce(+bias+res) + LN1(next)/LNf -> x, xnb
    k_mm_bf<<<6 * 16 * 4, blk, 0, stream>>>(hbb, wl + QKVSZ + OSZ + W1SZ, nullptr,
                                            po4, T, 768, 3072, 3, 4);
    const float* ng = (l < L - 1) ? ln1_g + (l + 1) * D : lnf_g;
    const float* nb_ = (l < L - 1) ? ln1_b + (l + 1) * D : lnf_b;
    k_redln<<<T, blk, 0, stream>>>(po4, 4, b2 + l * D, x, ng, nb_, xnb);
  }

  // LM head: bf16 gload path (shuffled emb in ws) if it fits, else fallback
  if (bigws)
    k_mm_gl<<<393 * 16, blk, 0, stream>>>(xnb, embS, lm_bias, out, T, V, 768);
  else
    k_mm_lmh<<<393 * 16, blk, 0, stream>>>(xnb, emb, lm_bias, out, T, V, 768);
}